// Round 1
// baseline (116.865 us; speedup 1.0000x reference)
//
#include <hip/hip_runtime.h>

// topk_mean pooling (k=2), fused single kernel. patch_ids are SORTED along
// seq, so each patch is a contiguous token run. Each block owns G consecutive
// patches of one batch row => one contiguous token stream per block:
//   - threads 0..G binary-search the G+1 run boundaries into LDS (no separate
//     seg_bounds kernel, no inter-kernel device sync),
//   - the token stream is consumed in D-deep chunks (D independent row loads
//     in flight => latency amortized D x instead of per-token stalls),
//   - patches are finalized (stored) as the stream crosses their boundary;
//     all finalize/boundary branches are block-uniform (no divergence).
// Semantics (faithful to reference): m1 = max over run; m2 = max over values
// STRICTLY below m1 (reference masks ALL copies of the max with -1e9);
//   n==0 -> 0 ; n==1 or k==1 -> m1 ; n>=2 -> 0.5*(m1 + max(m2, -1e9)).

#define NEG_INF (-1.0e9f)
#define G 4   // patches per block (contiguous token runs)
#define D 8   // pipeline depth: independent row loads in flight per thread

__global__ __launch_bounds__(128) void topk_mean_pool_fused(
    const float* __restrict__ h,
    const int*   __restrict__ pid,
    const int*   __restrict__ d_P,
    const int*   __restrict__ d_k,
    float*       __restrict__ out,
    int bs_seq, int pairs, int E)
{
    const int P   = *d_P;
    const int bs  = pairs / P;
    const int seq = bs_seq / bs;
    const int kk  = *d_k;
    const int Ed4 = E >> 2;               // float4 columns (128 for E=512)

    const int nblk  = (P + G - 1) / G;    // patch-groups per batch row
    const int slots = bs * nblk;

    __shared__ int sbd[G + 1];

    for (int slot = blockIdx.x; slot < slots; slot += gridDim.x) {
        const int b     = slot / nblk;
        const int g     = slot - b * nblk;
        const int p0    = g * G;                  // first patch of this block
        const int count = min(G, P - p0);         // patches actually owned

        // Boundaries: token range of patch (p0+i) is [sbd[i], sbd[i+1]).
        // lower_bound(p0+i) on the sorted row; for p0+i >= P this naturally
        // returns seq (all ids < P), which is exactly the stream end.
        if (threadIdx.x <= G) {
            const int  tgt = p0 + (int)threadIdx.x;
            const int* row = pid + (size_t)b * seq;
            int lo = 0, hi = seq;
            while (lo < hi) {
                const int mid = (lo + hi) >> 1;
                if (row[mid] < tgt) lo = mid + 1; else hi = mid;
            }
            sbd[threadIdx.x] = lo;
        }
        __syncthreads();

        const float4* hb   = (const float4*)h + (size_t)b * seq * Ed4;
        float4*       outb = (float4*)out + (size_t)(b * P + p0) * Ed4;

        for (int c = threadIdx.x; c < Ed4; c += blockDim.x) {
            const int s  = sbd[0];
            const int en = sbd[count];
            int    cur    = 0;
            int    pstart = s;
            int    pend   = sbd[1];
            float4 m1 = make_float4(-INFINITY, -INFINITY, -INFINITY, -INFINITY);
            float4 m2 = m1;

            auto finalize = [&]() {
                const int n = pend - pstart;
                float4 r;
                if (n == 0) {
                    r = make_float4(0.f, 0.f, 0.f, 0.f);
                } else if (n == 1 || kk == 1) {
                    r = m1;
                } else {
                    r.x = 0.5f * (m1.x + fmaxf(m2.x, NEG_INF));
                    r.y = 0.5f * (m1.y + fmaxf(m2.y, NEG_INF));
                    r.z = 0.5f * (m1.z + fmaxf(m2.z, NEG_INF));
                    r.w = 0.5f * (m1.w + fmaxf(m2.w, NEG_INF));
                }
                outb[(size_t)cur * Ed4 + c] = r;
                m1 = make_float4(-INFINITY, -INFINITY, -INFINITY, -INFINITY);
                m2 = m1;
                pstart = pend;
                ++cur;
                pend = (cur < count) ? sbd[cur + 1] : 0x7fffffff;
            };

            // leading (and possibly all) empty patches
            while (cur < count && pend == s) finalize();

            int t = s;
            while (t < en) {
                const int nload = min(D, en - t);
                float4 v[D];
#pragma unroll
                for (int d = 0; d < D; ++d)
                    if (d < nload) v[d] = hb[(size_t)(t + d) * Ed4 + c];
#pragma unroll
                for (int d = 0; d < D; ++d) {
                    if (d < nload) {
                        const float4 vv = v[d];
                        if (vv.x > m1.x) { m2.x = m1.x; m1.x = vv.x; }
                        else if (vv.x < m1.x && vv.x > m2.x) { m2.x = vv.x; }
                        if (vv.y > m1.y) { m2.y = m1.y; m1.y = vv.y; }
                        else if (vv.y < m1.y && vv.y > m2.y) { m2.y = vv.y; }
                        if (vv.z > m1.z) { m2.z = m1.z; m1.z = vv.z; }
                        else if (vv.z < m1.z && vv.z > m2.z) { m2.z = vv.z; }
                        if (vv.w > m1.w) { m2.w = m1.w; m1.w = vv.w; }
                        else if (vv.w < m1.w && vv.w > m2.w) { m2.w = vv.w; }
                        const int tn = t + d + 1;
                        while (cur < count && pend == tn) finalize();
                    }
                }
                t += nload;
            }
        }
        __syncthreads();   // protect sbd before next grid-stride slot
    }
}

extern "C" void kernel_launch(void* const* d_in, const int* in_sizes, int n_in,
                              void* d_out, int out_size, void* d_ws, size_t ws_size,
                              hipStream_t stream) {
    const float* h   = (const float*)d_in[0];
    const int*   pid = (const int*)d_in[1];
    const int*   d_P = (const int*)d_in[2];
    const int*   d_k = (const int*)d_in[3];
    float*       out = (float*)d_out;
    (void)d_ws; (void)ws_size; (void)n_in;

    const int h_elems = in_sizes[0];       // bs*seq*E
    const int bs_seq  = in_sizes[1];       // bs*seq
    const int E       = h_elems / bs_seq;  // 512
    const int pairs   = out_size / E;      // bs*P

    // grid ~= slots when P % G == 0; device grid-strides to cover any remainder
    const int grid = (pairs + G - 1) / G;
    topk_mean_pool_fused<<<dim3(grid), dim3(128), 0, stream>>>(
        h, pid, d_P, d_k, out, bs_seq, pairs, E);
}

// Round 2
// 106.862 us; speedup vs baseline: 1.0936x; 1.0936x over previous
//
#include <hip/hip_runtime.h>

// topk_mean pooling (k=2). patch_ids are SORTED along seq, so each patch is a
// contiguous token run. Two kernels:
//   A) seg_bounds_scatter: one thread per TOKEN detects run boundaries
//      (pid[t-1] != pid[t]) and writes bnd[p] = lower_bound(p) for the gap
//      range. No binary search, no dependent-load chains, 32768 threads
//      (vs 8192-thread/12-dependent-load search previously).
//   B) topk_mean_pool: one block (128 thr) per (b,p); boundaries are two
//      uniform scalar loads; token loop prefetches up to D=8 rows before
//      consuming => single HBM latency exposure for n<=8 (avg n is 4).
// Semantics (faithful to reference): m1 = max over run; m2 = max over values
// STRICTLY below m1 (reference masks ALL copies of the max with -1e9);
//   n==0 -> 0 ; n==1 or k==1 -> m1 ; n>=2 -> 0.5*(m1 + max(m2, -1e9)).

#define NEG_INF (-1.0e9f)
#define D 8   // prefetch depth: independent row loads in flight per thread

__global__ __launch_bounds__(256) void seg_bounds_scatter(
    const int* __restrict__ pid,
    const int* __restrict__ d_P,
    int*       __restrict__ bnd,   // [bs*P] lower_bound_b(p)
    int bs_seq, int pairs)
{
    const int P   = *d_P;
    const int bs  = pairs / P;
    const int seq = bs_seq / bs;

    const int idx = blockIdx.x * blockDim.x + threadIdx.x;
    if (idx >= bs_seq) return;
    const int b = idx / seq;
    const int t = idx - b * seq;

    const int* row  = pid + (size_t)b * seq;
    int*       brow = bnd + (size_t)b * P;
    const int  cur  = row[t];

    if (t == 0) {
        // lower_bound(p) == 0 for all p <= row[0]
        for (int p = 0; p <= cur; ++p) brow[p] = 0;
    } else {
        const int prev = row[t - 1];
        // lower_bound(p) == t for p in (prev, cur]
        for (int p = prev + 1; p <= cur; ++p) brow[p] = t;
    }
    if (t == seq - 1) {
        // lower_bound(p) == seq for p > row[seq-1]
        for (int p = cur + 1; p < P; ++p) brow[p] = seq;
    }
}

__global__ __launch_bounds__(128) void topk_mean_pool(
    const float* __restrict__ h,
    const int*   __restrict__ bnd,
    const int*   __restrict__ d_P,
    const int*   __restrict__ d_k,
    float*       __restrict__ out,
    int bs_seq, int pairs, int E)
{
    const int P   = *d_P;
    const int bs  = pairs / P;
    const int seq = bs_seq / bs;
    const int kk  = *d_k;

    const int pair = blockIdx.x;     // pair = b*P + p
    const int b    = pair / P;
    const int p    = pair - b * P;

    // Uniform (blockIdx-only) -> scalar loads.
    const int start = bnd[pair];
    const int end   = (p == P - 1) ? seq : bnd[pair + 1];
    const int n     = end - start;

    const int Ed4 = E >> 2;          // 128 for E=512
    const float4* hb   = (const float4*)h + (size_t)b * seq * Ed4;
    float4*       out4 = (float4*)out + (size_t)pair * Ed4;

    for (int c = threadIdx.x; c < Ed4; c += blockDim.x) {
        float4 r;
        if (n == 0) {
            r = make_float4(0.f, 0.f, 0.f, 0.f);
        } else {
            float4 m1 = make_float4(-INFINITY, -INFINITY, -INFINITY, -INFINITY);
            float4 m2 = m1;
            int t = start;
            while (t < end) {
                const int nload = min(D, end - t);
                float4 v[D];
                // issue all chunk loads before consuming any -> one latency
                // exposure per chunk (n<=8: one exposure total)
#pragma unroll
                for (int d = 0; d < D; ++d)
                    if (d < nload) v[d] = hb[(size_t)(t + d) * Ed4 + c];
#pragma unroll
                for (int d = 0; d < D; ++d) {
                    if (d < nload) {
                        const float4 vv = v[d];
                        if (vv.x > m1.x) { m2.x = m1.x; m1.x = vv.x; }
                        else if (vv.x < m1.x && vv.x > m2.x) { m2.x = vv.x; }
                        if (vv.y > m1.y) { m2.y = m1.y; m1.y = vv.y; }
                        else if (vv.y < m1.y && vv.y > m2.y) { m2.y = vv.y; }
                        if (vv.z > m1.z) { m2.z = m1.z; m1.z = vv.z; }
                        else if (vv.z < m1.z && vv.z > m2.z) { m2.z = vv.z; }
                        if (vv.w > m1.w) { m2.w = m1.w; m1.w = vv.w; }
                        else if (vv.w < m1.w && vv.w > m2.w) { m2.w = vv.w; }
                    }
                }
                t += nload;
            }
            if (n == 1 || kk == 1) {
                r = m1;
            } else {
                r.x = 0.5f * (m1.x + fmaxf(m2.x, NEG_INF));
                r.y = 0.5f * (m1.y + fmaxf(m2.y, NEG_INF));
                r.z = 0.5f * (m1.z + fmaxf(m2.z, NEG_INF));
                r.w = 0.5f * (m1.w + fmaxf(m2.w, NEG_INF));
            }
        }
        out4[c] = r;
    }
}

extern "C" void kernel_launch(void* const* d_in, const int* in_sizes, int n_in,
                              void* d_out, int out_size, void* d_ws, size_t ws_size,
                              hipStream_t stream) {
    const float* h   = (const float*)d_in[0];
    const int*   pid = (const int*)d_in[1];
    const int*   d_P = (const int*)d_in[2];
    const int*   d_k = (const int*)d_in[3];
    float*       out = (float*)d_out;
    int*         bnd = (int*)d_ws;
    (void)n_in; (void)ws_size;

    const int h_elems = in_sizes[0];       // bs*seq*E
    const int bs_seq  = in_sizes[1];       // bs*seq
    const int E       = h_elems / bs_seq;  // 512
    const int pairs   = out_size / E;      // bs*P

    {
        dim3 grid((bs_seq + 255) / 256), block(256);
        seg_bounds_scatter<<<grid, block, 0, stream>>>(pid, d_P, bnd,
                                                       bs_seq, pairs);
    }
    {
        dim3 grid(pairs), block(128);
        topk_mean_pool<<<grid, block, 0, stream>>>(h, bnd, d_P, d_k, out,
                                                   bs_seq, pairs, E);
    }
}